// Round 6
// baseline (424.415 us; speedup 1.0000x reference)
//
#include <hip/hip_runtime.h>
#include <hip/hip_bf16.h>

typedef __bf16 v8bf __attribute__((ext_vector_type(8)));
typedef float v4f __attribute__((ext_vector_type(4)));

#define GBL_AS(p) ((const __attribute__((address_space(1))) unsigned int*)(p))
#define LDS_AS(p) ((__attribute__((address_space(3))) unsigned int*)(p))

// s_waitcnt immediates: lgkmcnt=15 (no wait) bits[11:8], expcnt=7 bits[6:4],
// vmcnt low bits[3:0].
#define WAIT_VM4() __builtin_amdgcn_s_waitcnt(0x0F74)  // vmcnt(4)
#define WAIT_VM6() __builtin_amdgcn_s_waitcnt(0x0F76)  // vmcnt(6)
#define WAIT_VM0() __builtin_amdgcn_s_waitcnt(0x0F70)  // vmcnt(0)

// ---------------- fp32 -> bf16 cast (x) ----------------
__global__ void cast_f32_bf16(const float* __restrict__ src,
                              __hip_bfloat16* __restrict__ dst, int n) {
  int i = (blockIdx.x * 256 + threadIdx.x) * 4;
  if (i >= n) return;
  float4 f = *(const float4*)(src + i);
  union { __hip_bfloat16 h[4]; uint2 u; } pk;
  pk.h[0] = __float2bfloat16(f.x);
  pk.h[1] = __float2bfloat16(f.y);
  pk.h[2] = __float2bfloat16(f.z);
  pk.h[3] = __float2bfloat16(f.w);
  *(uint2*)(dst + i) = pk.u;
}

// ---------------- fp32 -> bf16 cast, 3 weight tensors ----------------
__global__ void cast_w3(const float* __restrict__ a, const float* __restrict__ b,
                        const float* __restrict__ c, __hip_bfloat16* __restrict__ dst) {
  int seg = blockIdx.x >> 10;
  const float* src = seg == 0 ? a : (seg == 1 ? b : c);
  int i = ((blockIdx.x & 1023) * 256 + threadIdx.x) * 4;
  float4 f = *(const float4*)(src + i);
  union { __hip_bfloat16 h[4]; uint2 u; } pk;
  pk.h[0] = __float2bfloat16(f.x);
  pk.h[1] = __float2bfloat16(f.y);
  pk.h[2] = __float2bfloat16(f.z);
  pk.h[3] = __float2bfloat16(f.w);
  *(uint2*)(dst + seg * 1048576 + i) = pk.u;
}

// ---------------- projection GEMM: 256x128 tile (r1-proven, unchanged) ----------------
__global__ __launch_bounds__(256, 2)
void gemm_proj(const __hip_bfloat16* __restrict__ A, int lda,
               const __hip_bfloat16* __restrict__ B, long sBb, int ldb,
               __hip_bfloat16* __restrict__ C, long sCb, int ldc,
               float scale, __hip_bfloat16* __restrict__ vTp) {
  const int tid = threadIdx.x;
  const int l = tid & 63, w = tid >> 6;
  const int z  = blockIdx.x >> 3;
  const int nb = (blockIdx.x & 7) << 7;
  const int mb = blockIdx.y << 8;

  B += (long)z * sBb;

  __shared__ alignas(16) __hip_bfloat16 As[3][256 * 32];
  __shared__ alignas(16) __hip_bfloat16 Bs[3][128 * 32];

  v4f acc[8][4] = {};
  const int wm = (w >> 1) << 7;
  const int wn = (w & 1) << 6;

  const int qa0 = 0 * 256 + w * 64 + l, ra0 = qa0 >> 2;
  const int qa1 = 1 * 256 + w * 64 + l, ra1 = qa1 >> 2;
  const int qa2 = 2 * 256 + w * 64 + l, ra2 = qa2 >> 2;
  const int qa3 = 3 * 256 + w * 64 + l, ra3 = qa3 >> 2;
  const __hip_bfloat16* sA0 = A + (long)(mb + ra0) * lda + (((qa0 & 3) ^ ((ra0 >> 1) & 3)) << 3);
  const __hip_bfloat16* sA1 = A + (long)(mb + ra1) * lda + (((qa1 & 3) ^ ((ra1 >> 1) & 3)) << 3);
  const __hip_bfloat16* sA2 = A + (long)(mb + ra2) * lda + (((qa2 & 3) ^ ((ra2 >> 1) & 3)) << 3);
  const __hip_bfloat16* sA3 = A + (long)(mb + ra3) * lda + (((qa3 & 3) ^ ((ra3 >> 1) & 3)) << 3);
  const int qb0 = 0 * 256 + w * 64 + l, rb0 = qb0 >> 2;
  const int qb1 = 1 * 256 + w * 64 + l, rb1 = qb1 >> 2;
  const __hip_bfloat16* sB0 = B + (long)(nb + rb0) * ldb + (((qb0 & 3) ^ ((rb0 >> 1) & 3)) << 3);
  const __hip_bfloat16* sB1 = B + (long)(nb + rb1) * ldb + (((qb1 & 3) ^ ((rb1 >> 1) & 3)) << 3);

  const int arow = wm + (l & 15);
  const int ldsA = arow * 32 + ((((l >> 4) ^ ((arow >> 1) & 3))) << 3);
  const int brow = wn + (l & 15);
  const int ldsB = brow * 32 + ((((l >> 4) ^ ((brow >> 1) & 3))) << 3);

#define STAGE_P(K0, BUF) do {                                                   \
    __builtin_amdgcn_global_load_lds(GBL_AS(sA0 + (K0)),                        \
        LDS_AS(&As[BUF][0 * 2048 + w * 512]), 16, 0, 0);                        \
    __builtin_amdgcn_global_load_lds(GBL_AS(sA1 + (K0)),                        \
        LDS_AS(&As[BUF][1 * 2048 + w * 512]), 16, 0, 0);                        \
    __builtin_amdgcn_global_load_lds(GBL_AS(sA2 + (K0)),                        \
        LDS_AS(&As[BUF][2 * 2048 + w * 512]), 16, 0, 0);                        \
    __builtin_amdgcn_global_load_lds(GBL_AS(sA3 + (K0)),                        \
        LDS_AS(&As[BUF][3 * 2048 + w * 512]), 16, 0, 0);                        \
    __builtin_amdgcn_global_load_lds(GBL_AS(sB0 + (K0)),                        \
        LDS_AS(&Bs[BUF][0 * 2048 + w * 512]), 16, 0, 0);                        \
    __builtin_amdgcn_global_load_lds(GBL_AS(sB1 + (K0)),                        \
        LDS_AS(&Bs[BUF][1 * 2048 + w * 512]), 16, 0, 0);                        \
  } while (0)

#define COMPUTE_P(BI) do {                                                      \
    v8bf af[8], bfr[4];                                                         \
    _Pragma("unroll")                                                           \
    for (int i = 0; i < 8; ++i)                                                 \
      af[i]  = *(const v8bf*)(&As[BI][ldsA + i * 512]);                         \
    _Pragma("unroll")                                                           \
    for (int j = 0; j < 4; ++j)                                                 \
      bfr[j] = *(const v8bf*)(&Bs[BI][ldsB + j * 512]);                         \
    _Pragma("unroll")                                                           \
    for (int i = 0; i < 8; ++i)                                                 \
      _Pragma("unroll")                                                         \
      for (int j = 0; j < 4; ++j)                                               \
        acc[i][j] = __builtin_amdgcn_mfma_f32_16x16x32_bf16(af[i], bfr[j],      \
                                                            acc[i][j], 0, 0, 0);\
  } while (0)

#define KITER_P(IT) do {                                                        \
    if constexpr ((IT) < 31) WAIT_VM6(); else WAIT_VM0();                       \
    __builtin_amdgcn_s_barrier();                                               \
    if constexpr ((IT) < 30) STAGE_P((IT) * 32 + 64, ((IT) + 2) % 3);           \
    COMPUTE_P((IT) % 3);                                                        \
  } while (0)

  STAGE_P(0, 0);
  STAGE_P(32, 1);
  KITER_P(0);  KITER_P(1);  KITER_P(2);  KITER_P(3);  KITER_P(4);  KITER_P(5);
  KITER_P(6);  KITER_P(7);  KITER_P(8);  KITER_P(9);  KITER_P(10); KITER_P(11);
  KITER_P(12); KITER_P(13); KITER_P(14); KITER_P(15); KITER_P(16); KITER_P(17);
  KITER_P(18); KITER_P(19); KITER_P(20); KITER_P(21); KITER_P(22); KITER_P(23);
  KITER_P(24); KITER_P(25); KITER_P(26); KITER_P(27); KITER_P(28); KITER_P(29);
  KITER_P(30); KITER_P(31);
#undef KITER_P
#undef COMPUTE_P
#undef STAGE_P

  const int col0 = nb + wn + (l & 15);
  const int row0 = mb + wm + ((l >> 4) << 2);
  if (z < 2) {
    __hip_bfloat16* Cz = C + (long)z * sCb;
#pragma unroll
    for (int i = 0; i < 8; ++i)
#pragma unroll
      for (int r = 0; r < 4; ++r) {
        long ro = (long)(row0 + i * 16 + r) * ldc;
#pragma unroll
        for (int j = 0; j < 4; ++j)
          Cz[ro + col0 + j * 16] = __float2bfloat16(acc[i][j][r] * scale);
      }
  } else {
    const long b = row0 >> 11;
    const int seq0 = row0 & 2047;
#pragma unroll
    for (int i = 0; i < 8; ++i)
#pragma unroll
      for (int j = 0; j < 4; ++j) {
        union { __hip_bfloat16 h[4]; uint2 u; } pk;
#pragma unroll
        for (int r = 0; r < 4; ++r) pk.h[r] = __float2bfloat16(acc[i][j][r]);
        *(uint2*)(vTp + b * 2097152 + (long)(col0 + j * 16) * 2048 +
                  (seq0 + i * 16)) = pk.u;
      }
  }
}

// ---------------- merged score+pv persistent ticketed kernel ----------------
// THEORY (r6): score/pv kernels launch all blocks simultaneously with zero
// backlog -> resident blocks run phase-locked (stalls align) -> effective
// concurrency ~1 despite 2-3 resident (proj's 1.5-round grid gets ~2).
// Fix: 768 persistent blocks (exactly 3/CU at 48KB LDS) pop 1056 work tickets:
//   t in [0,544): score tile, ordered m-ascending (item -> (m, z, n<=m))
//   t in [544,1056): pv tile, m-ascending (item -> (m, z, nc))
// pv(z,m) gated on done[z*16+m]==m+1 via device-scope release/acquire
// (covers P-tiles AND fused row-sums). Deadlock-free for ANY residency>=1:
// score tickets strictly precede pv tickets, so every spinning consumer's
// producers are already claimed by running blocks. GEMM bodies byte-identical
// to the r4-proven kernels (zero numerics change).
__global__ __launch_bounds__(256, 3)
void attn_sp(const __hip_bfloat16* __restrict__ q,
             const __hip_bfloat16* __restrict__ kk,
             __hip_bfloat16* __restrict__ P,
             const __hip_bfloat16* __restrict__ vT,
             float* __restrict__ out,
             float* __restrict__ sums,
             int* __restrict__ ticket,
             int* __restrict__ done) {
  const int tid = threadIdx.x;
  const int l = tid & 63, w = tid >> 6;

  __shared__ alignas(16) __hip_bfloat16 As[3][128 * 32];
  __shared__ alignas(16) __hip_bfloat16 Bs[3][128 * 32];
  __shared__ int s_t;

  const int wm = (w >> 1) * 64, wn = (w & 1) * 64;
  const int cb0 = w * 64;
  const int q0i = cb0 + l, r0s = q0i >> 2;
  const int c0s = ((q0i & 3) ^ ((r0s >> 1) & 3)) << 3;
  const int cb1 = 256 + w * 64;
  const int q1i = cb1 + l, r1s = q1i >> 2;
  const int c1s = ((q1i & 3) ^ ((r1s >> 1) & 3)) << 3;
  const int arow = wm + (l & 15);
  const int ldsA = arow * 32 + ((((l >> 4) ^ ((arow >> 1) & 3))) << 3);
  const int brow = wn + (l & 15);
  const int ldsB = brow * 32 + ((((l >> 4) ^ ((brow >> 1) & 3))) << 3);

  for (;;) {
    __syncthreads();                       // guards LDS + s_t reuse across items
    if (tid == 0) s_t = atomicAdd(ticket, 1);
    __syncthreads();
    const int t = s_t;
    if (t >= 1056) return;

    if (t < 544) {
      // ---- SCORE item: (m asc, z, n<=m); cum(m) = 2m(m+1) ----
      int m = (int)((__builtin_sqrtf(2.0f * t + 1.0f) - 1.0f) * 0.5f);
      while (2 * (m + 1) * (m + 2) <= t) ++m;
      while (2 * m * (m + 1) > t) --m;
      const int rem = t - 2 * m * (m + 1);
      const int z = rem / (m + 1);
      const int n = rem - z * (m + 1);
      const int mb = m << 7, nb = n << 7;

      const __hip_bfloat16* Az = q  + (long)z * 2097152;
      const __hip_bfloat16* Bz = kk + (long)z * 2097152;
      const __hip_bfloat16* Arow0 = Az + (long)(mb + r0s) * 1024 + c0s;
      const __hip_bfloat16* Arow1 = Az + (long)(mb + r1s) * 1024 + c1s;
      const __hip_bfloat16* Brow0 = Bz + (long)(nb + r0s) * 1024 + c0s;
      const __hip_bfloat16* Brow1 = Bz + (long)(nb + r1s) * 1024 + c1s;

      v4f acc[4][4] = {};

#define STAGE_S(K0, BUF) do {                                                   \
    __builtin_amdgcn_global_load_lds(GBL_AS(Arow0 + (K0)),                      \
        LDS_AS(&As[BUF][cb0 * 8]), 16, 0, 0);                                   \
    __builtin_amdgcn_global_load_lds(GBL_AS(Brow0 + (K0)),                      \
        LDS_AS(&Bs[BUF][cb0 * 8]), 16, 0, 0);                                   \
    __builtin_amdgcn_global_load_lds(GBL_AS(Arow1 + (K0)),                      \
        LDS_AS(&As[BUF][cb1 * 8]), 16, 0, 0);                                   \
    __builtin_amdgcn_global_load_lds(GBL_AS(Brow1 + (K0)),                      \
        LDS_AS(&Bs[BUF][cb1 * 8]), 16, 0, 0);                                   \
  } while (0)

#define COMPUTE_S(BI) do {                                                      \
    v8bf af[4], bfr[4];                                                         \
    _Pragma("unroll")                                                           \
    for (int i = 0; i < 4; ++i) {                                               \
      af[i]  = *(const v8bf*)(&As[BI][ldsA + i * 512]);                         \
      bfr[i] = *(const v8bf*)(&Bs[BI][ldsB + i * 512]);                         \
    }                                                                           \
    _Pragma("unroll")                                                           \
    for (int i = 0; i < 4; ++i)                                                 \
      _Pragma("unroll")                                                         \
      for (int j = 0; j < 4; ++j)                                               \
        acc[i][j] = __builtin_amdgcn_mfma_f32_16x16x32_bf16(af[i], bfr[j],      \
                                                            acc[i][j], 0, 0, 0);\
  } while (0)

#define KITER_S(IT) do {                                                        \
    if constexpr ((IT) < 31) WAIT_VM4(); else WAIT_VM0();                       \
    __builtin_amdgcn_s_barrier();                                               \
    if constexpr ((IT) < 30) STAGE_S((IT) * 32 + 64, ((IT) + 2) % 3);           \
    COMPUTE_S((IT) % 3);                                                        \
  } while (0)

      STAGE_S(0, 0);
      STAGE_S(32, 1);
      KITER_S(0);  KITER_S(1);  KITER_S(2);  KITER_S(3);  KITER_S(4);
      KITER_S(5);  KITER_S(6);  KITER_S(7);  KITER_S(8);  KITER_S(9);
      KITER_S(10); KITER_S(11); KITER_S(12); KITER_S(13); KITER_S(14);
      KITER_S(15); KITER_S(16); KITER_S(17); KITER_S(18); KITER_S(19);
      KITER_S(20); KITER_S(21); KITER_S(22); KITER_S(23); KITER_S(24);
      KITER_S(25); KITER_S(26); KITER_S(27); KITER_S(28); KITER_S(29);
      KITER_S(30); KITER_S(31);
#undef KITER_S
#undef COMPUTE_S
#undef STAGE_S

      // epilogue: exp + causal mask + bf16 store + fused row-sum atomics
      __hip_bfloat16* Cz = P + (long)z * 4194304;
      float* srow = sums + z * 2048;
      const int col0 = nb + wn + (l & 15);
      const int row0 = mb + wm + ((l >> 4) << 2);
#pragma unroll
      for (int i = 0; i < 4; ++i)
#pragma unroll
        for (int r = 0; r < 4; ++r) {
          const int mm = row0 + i * 16 + r;
          const long ro = (long)mm * 2048;
          float sp = 0.f;
#pragma unroll
          for (int j = 0; j < 4; ++j) {
            const int nn = col0 + j * 16;
            float pv = (nn <= mm) ? __expf(acc[i][j][r] * 0.03125f) : 0.0f;
            sp += pv;
            Cz[ro + nn] = __float2bfloat16(pv);
          }
          sp += __shfl_xor(sp, 1);
          sp += __shfl_xor(sp, 2);
          sp += __shfl_xor(sp, 4);
          sp += __shfl_xor(sp, 8);
          if ((l & 15) == 0) atomicAdd(&srow[mm], sp);
        }

      // publish: all P stores + sum atomics visible, then release the flag
      __threadfence();
      __syncthreads();
      if (tid == 0)
        __hip_atomic_fetch_add(&done[z * 16 + m], 1,
                               __ATOMIC_RELEASE, __HIP_MEMORY_SCOPE_AGENT);
    } else {
      // ---- PV item: u = t-544; (m asc, z, nc) ----
      const int u = t - 544;
      const int m = u >> 5;
      const int rem = u & 31;
      const int z = rem >> 3, nc = rem & 7;
      const int mb = m << 7, nb = nc << 7;
      const int kend = (m + 1) << 7;

      // gate on all m+1 producer tiles of row-panel (z,m)
      if (tid == 0) {
        while (__hip_atomic_load(&done[z * 16 + m],
                                 __ATOMIC_ACQUIRE, __HIP_MEMORY_SCOPE_AGENT) < m + 1)
          __builtin_amdgcn_s_sleep(16);
      }
      __syncthreads();
      {  // per-wave acquire so every wave gets its cache invalidate
        int d = __hip_atomic_load(&done[z * 16 + m],
                                  __ATOMIC_ACQUIRE, __HIP_MEMORY_SCOPE_AGENT);
        asm volatile("" : : "v"(d));
      }

      const __hip_bfloat16* Az = P  + (long)z * 4194304;   // lda 2048
      const __hip_bfloat16* Bz = vT + (long)z * 2097152;   // ldb 2048
      const __hip_bfloat16* Arow0 = Az + (long)(mb + r0s) * 2048 + c0s;
      const __hip_bfloat16* Arow1 = Az + (long)(mb + r1s) * 2048 + c1s;
      const __hip_bfloat16* Brow0 = Bz + (long)(nb + r0s) * 2048 + c0s;
      const __hip_bfloat16* Brow1 = Bz + (long)(nb + r1s) * 2048 + c1s;

      v4f acc[4][4] = {};
      auto stage = [&](int k0, int buf) {
        __builtin_amdgcn_global_load_lds(GBL_AS(Arow0 + k0),
            LDS_AS(&As[buf][cb0 * 8]), 16, 0, 0);
        __builtin_amdgcn_global_load_lds(GBL_AS(Brow0 + k0),
            LDS_AS(&Bs[buf][cb0 * 8]), 16, 0, 0);
        __builtin_amdgcn_global_load_lds(GBL_AS(Arow1 + k0),
            LDS_AS(&As[buf][cb1 * 8]), 16, 0, 0);
        __builtin_amdgcn_global_load_lds(GBL_AS(Brow1 + k0),
            LDS_AS(&Bs[buf][cb1 * 8]), 16, 0, 0);
      };
      stage(0, 0);
      if (32 < kend) stage(32, 1);
      int bi = 0;
      for (int k0 = 0; k0 < kend; k0 += 32) {
        if (k0 + 32 < kend) WAIT_VM4(); else WAIT_VM0();
        __builtin_amdgcn_s_barrier();
        if (k0 + 64 < kend) stage(k0 + 64, bi == 0 ? 2 : bi - 1);
        v8bf af[4], bfr[4];
#pragma unroll
        for (int i = 0; i < 4; ++i) {
          af[i]  = *(const v8bf*)(&As[bi][ldsA + i * 512]);
          bfr[i] = *(const v8bf*)(&Bs[bi][ldsB + i * 512]);
        }
#pragma unroll
        for (int i = 0; i < 4; ++i)
#pragma unroll
          for (int jj = 0; jj < 4; ++jj)
            acc[i][jj] = __builtin_amdgcn_mfma_f32_16x16x32_bf16(af[i], bfr[jj],
                                                                 acc[i][jj], 0, 0, 0);
        bi = (bi == 2) ? 0 : bi + 1;
      }

      // epilogue: divide by rowsum, fp32 stores
      float* Cz = out + (long)z * 2097152;
      const float* srow = sums + z * 2048;
      const int col0 = nb + wn + (l & 15);
      const int row0 = mb + wm + ((l >> 4) << 2);
#pragma unroll
      for (int i = 0; i < 4; ++i)
#pragma unroll
        for (int r = 0; r < 4; ++r) {
          const int mr = row0 + i * 16 + r;
          const float sc = 1.0f / srow[mr];
          const long ro = (long)mr * 1024;
#pragma unroll
          for (int jj = 0; jj < 4; ++jj)
            Cz[ro + col0 + jj * 16] = acc[i][jj][r] * sc;
        }
    }
  }
}

// ---------------- launch ----------------
extern "C" void kernel_launch(void* const* d_in, const int* in_sizes, int n_in,
                              void* d_out, int out_size, void* d_ws, size_t ws_size,
                              hipStream_t stream) {
  const float* x  = (const float*)d_in[0];
  const float* Wq = (const float*)d_in[1];
  const float* Wk = (const float*)d_in[2];
  const float* Wv = (const float*)d_in[3];
  float* out = (float*)d_out;
  char* ws = (char*)d_ws;

  // ws layout (bytes):
  //   qkv bf16 [3][8192][1024]   @ 0          (48 MB; v-slice unused)
  //   vT  bf16 [4][1024][2048]   @ 50331648   (16 MB)
  //   xb  bf16 [8192][1024]      @ 67108864   (16 MB, dead after proj)
  //   Wb  bf16 [3][1024][1024]   @ 83886080   ( 6 MB, dead after proj)
  //   P   bf16 [4][2048][2048]   @ 67108864   (32 MB, overlaps dead xb/Wb)
  //   sums fp32 [8192]           @ 100663296  (32 KB)
  //   ticket int                 @ 100696064
  //   done int[64]               @ 100696128
  __hip_bfloat16* qkv = (__hip_bfloat16*)ws;
  __hip_bfloat16* vT  = (__hip_bfloat16*)(ws + 50331648);
  __hip_bfloat16* xb  = (__hip_bfloat16*)(ws + 67108864);
  __hip_bfloat16* Wb  = (__hip_bfloat16*)(ws + 83886080);
  __hip_bfloat16* P   = (__hip_bfloat16*)(ws + 67108864);
  float* sums         = (float*)(ws + 100663296);
  int* ticket         = (int*)(ws + 100696064);
  int* done           = (int*)(ws + 100696128);

  // zero sums + ticket + done in one memset (33 KB)
  hipMemsetAsync(sums, 0, 33792, stream);

  cast_f32_bf16<<<8192, 256, 0, stream>>>(x, xb, 8388608);
  cast_w3<<<3072, 256, 0, stream>>>(Wq, Wk, Wv, Wb);

  // qkv projections; z==2 (V) written transposed into vT by the epilogue
  gemm_proj<<<dim3(24, 32, 1), 256, 0, stream>>>(
      xb, 1024, Wb, 1048576L, 1024, qkv, 8388608L, 1024, 1.0f, vT);

  // merged score+pv: 768 persistent blocks (3/CU), 1056 tickets
  attn_sp<<<dim3(768, 1, 1), 256, 0, stream>>>(
      qkv, qkv + 8388608, P, vT, out, sums, ticket, done);
}